// Round 6
// baseline (814.959 us; speedup 1.0000x reference)
//
#include <hip/hip_runtime.h>
#include <math.h>

#define D_OPT   128
#define N_SIM   2048
#define M_STEPS 64
#define HID     64

// Round 12: ILP x2 — 128 elements/block (8 mt tiles per wave).
// R11 (z-prefetch + lgkm-only barrier) was exactly flat -> barrier-drain
// theory dead. Counters: VALU 72 / MFMA 57 / occ 42.7% (4 waves/SIMD,
// total regs 86..128) -> ~35% dependency bubbles in the MFMA->pack->MFMA
// ladder. Fix: more independent ladders per wave instead of more waves.
// Each block now covers 128 elements; each wave runs 8 independent mt
// ladders per step (unroll 2), halving per-element barrier/update overhead.
// Pipeline unchanged (validated): L1 = mfma 16x16x16f16 (bias k-slot 3);
// L2 = 2x mfma 16x16x32 (baked k-permutation); L3 = 2x mfma, w3 row 0.

typedef _Float16 f16x8 __attribute__((ext_vector_type(8)));
typedef _Float16 f16x4 __attribute__((ext_vector_type(4)));
typedef _Float16 f16x2 __attribute__((ext_vector_type(2)));
typedef float    f32x4 __attribute__((ext_vector_type(4)));
typedef unsigned int u32;
typedef u32 u32x2 __attribute__((ext_vector_type(2)));
typedef u32 u32x4 __attribute__((ext_vector_type(4)));

__device__ __forceinline__ u32 pk2u(float a, float b) {
#if __has_builtin(__builtin_amdgcn_cvt_pkrtz)
    return __builtin_bit_cast(u32, __builtin_amdgcn_cvt_pkrtz(a, b));
#else
    f16x2 p; p[0] = (_Float16)a; p[1] = (_Float16)b;
    return __builtin_bit_cast(u32, p);
#endif
}

__device__ __forceinline__ u32 pk_relu_cvt(float a, float b) {
    f16x2 p = __builtin_bit_cast(f16x2, pk2u(a, b));
    const f16x2 z = { (_Float16)0.0f, (_Float16)0.0f };
#if __has_builtin(__builtin_elementwise_max)
    p = __builtin_elementwise_max(p, z);
#else
    p[0] = p[0] > z[0] ? p[0] : z[0];
    p[1] = p[1] > z[1] ? p[1] : z[1];
#endif
    return __builtin_bit_cast(u32, p);
}

__global__ __launch_bounds__(256, 4) void nsde_kernel(
    const float* __restrict__ S0p, const float* __restrict__ Kp,
    const float* __restrict__ Tp,  const float* __restrict__ rfp,
    const float* __restrict__ V0p, const float* __restrict__ rhop,
    const float* __restrict__ Z1,  const float* __restrict__ Z2r,
    const float* __restrict__ W1,  const float* __restrict__ B1,
    const float* __restrict__ W2,  const float* __restrict__ B2,
    const float* __restrict__ W3,  const float* __restrict__ B3,
    float* __restrict__ out)
{
    __shared__ float nvp[2][4][128];  // [buf][net][element] = raw o, 4 KB
    __shared__ u32x2 pkx[4][128];     // [wave][element] {pk(S,V), pk(dt*s,1)}, 4 KB

    const int tid  = threadIdx.x;
    const int wave = tid >> 6;        // wave == net
    const int lane = tid & 63;
    const int q    = lane >> 4;
    const int mA   = lane & 15;
    const float rf = rfp[0];

    const float* w1g = W1 + wave * 256;   // [4][64]
    const float* b1g = B1 + wave * 64;
    const float* w2g = W2 + wave * 4096;  // [64][64] (h, g)
    const float* b2g = B2 + wave * 64;
    const float* w3g = W3 + wave * 64;    // [64]

    // ---------------- constant fragments (register-resident) ----------------
    // L1 (K=16): A[row=mA][k=q*4+j]; q==0 holds {wS, wV, wt, b1+rf*w_rf}.
    f16x4 A1[4];
    #pragma unroll
    for (int t = 0; t < 4; ++t) {
        f16x4 a = { (_Float16)0.0f, (_Float16)0.0f, (_Float16)0.0f, (_Float16)0.0f };
        if (q == 0) {
            const int h = t * 16 + mA;
            a[0] = (_Float16)w1g[0 * 64 + h];                       // S weight
            a[1] = (_Float16)w1g[1 * 64 + h];                       // V weight
            a[2] = (_Float16)w1g[3 * 64 + h];                       // dt*j weight
            a[3] = (_Float16)fmaf(rf, w1g[2 * 64 + h], b1g[h]);     // bias (x1.0)
        }
        A1[t] = a;
    }

    // L2 (K=32): A[row -> g=gt*16+mA][slot (kt,q*8+j) -> h1=H(kt,q*8+j)]
    f16x8 A2[4][2];
    #pragma unroll
    for (int gt = 0; gt < 4; ++gt)
        #pragma unroll
        for (int kt = 0; kt < 2; ++kt) {
            f16x8 a;
            #pragma unroll
            for (int j = 0; j < 8; ++j) {
                const int h1 = (2 * kt + (j >> 2)) * 16 + 4 * q + (j & 3);
                a[j] = (_Float16)w2g[h1 * 64 + gt * 16 + mA];
            }
            A2[gt][kt] = a;
        }

    // L3 (K=32 x2): row 0 = w3 (same baked permutation), other rows zero.
    f16x8 A3[2];
    #pragma unroll
    for (int kt = 0; kt < 2; ++kt) {
        f16x8 a;
        #pragma unroll
        for (int j = 0; j < 8; ++j) a[j] = (_Float16)0.0f;
        if (mA == 0) {
            #pragma unroll
            for (int j = 0; j < 8; ++j) {
                const int g = (2 * kt + (j >> 2)) * 16 + 4 * q + (j & 3);
                a[j] = (_Float16)w3g[g];
            }
        }
        A3[kt] = a;
    }

    // L2 bias C-splats (row = 4q+r); L1/L3 use zero C.
    f32x4 cinit2[4];
    #pragma unroll
    for (int t = 0; t < 4; ++t)
        #pragma unroll
        for (int r = 0; r < 4; ++r)
            cinit2[t][r] = b2g[t * 16 + 4 * q + r];
    const f32x4 zc = { 0.0f, 0.0f, 0.0f, 0.0f };

    // b3 per net (wave-uniform -> SGPRs), added in update phase.
    const float b3n0 = B3[0], b3n1 = B3[1], b3n2 = B3[2], b3n3 = B3[3];

    // ---------------- per-element state (2 elements per lane) ----------------
    const int ebase = blockIdx.x * 128;
    const int dA_ = (ebase + lane) & (D_OPT - 1);
    const int dB_ = (ebase + 64 + lane) & (D_OPT - 1);
    const float dtA  = Tp[dA_] * (1.0f / (float)M_STEPS);
    const float dtB  = Tp[dB_] * (1.0f / (float)M_STEPS);
    const float sdtA = sqrtf(dtA);
    const float sdtB = sqrtf(dtB);

    float SregA = S0p[dA_], SregB = S0p[dB_];
    float VregA = V0p[0],   VregB = V0p[0];
    {
        u32x2 pk0;
        pk0[0] = pk2u(SregA, VregA);
        pk0[1] = pk2u(0.0f, 1.0f);
        pkx[wave][lane] = pk0;
        u32x2 pk1;
        pk1[0] = pk2u(SregB, VregB);
        pk1[1] = pk2u(0.0f, 1.0f);
        pkx[wave][64 + lane] = pk1;
    }

    const float rho   = rhop[0];
    const float rho_c = sqrtf(1.0f - rho * rho);
    const size_t estep = (size_t)N_SIM * D_OPT;
    const float* z1p = Z1  + (size_t)ebase + (size_t)lane;
    const float* z2p = Z2r + (size_t)ebase + (size_t)lane;

    float z1cA = z1p[0], z1cB = z1p[64];
    float z2cA = z2p[0], z2cB = z2p[64];
    z1p += estep; z2p += estep;

    #pragma unroll 1
    for (int s = 0; s < M_STEPS; ++s) {
        // prefetch next-step z (stays in flight across the lgkm-only barrier)
        const float z1nA = z1p[0], z1nB = z1p[64];
        const float z2nA = z2p[0], z2nB = z2p[64];
        const size_t adv = (s < M_STEPS - 2) ? estep : (size_t)0;
        z1p += adv; z2p += adv;

        #pragma unroll 2
        for (int mt = 0; mt < 8; ++mt) {
            // feature B-fragment = raw exchange word (zero VALU)
            const u32x2 pksv = pkx[wave][mt * 16 + mA];
            const f16x4 B1f = __builtin_bit_cast(f16x4, pksv);

            // L1 -> pack relu(h1) into B2 (adjacent acc pairs = baked slots)
            u32x4 b2u[2];
            #pragma unroll
            for (int t = 0; t < 4; ++t) {
                const f32x4 acc = __builtin_amdgcn_mfma_f32_16x16x16f16(
                                      A1[t], B1f, zc, 0, 0, 0);
                b2u[t >> 1][(t & 1) * 2 + 0] = pk_relu_cvt(acc[0], acc[1]);
                b2u[t >> 1][(t & 1) * 2 + 1] = pk_relu_cvt(acc[2], acc[3]);
            }
            const f16x8 B2f0 = __builtin_bit_cast(f16x8, b2u[0]);
            const f16x8 B2f1 = __builtin_bit_cast(f16x8, b2u[1]);

            // L2 -> pack relu(h2) into B3
            u32x4 b3u[2];
            #pragma unroll
            for (int gt = 0; gt < 4; ++gt) {
                f32x4 acc = __builtin_amdgcn_mfma_f32_16x16x32_f16(
                                A2[gt][0], B2f0, cinit2[gt], 0, 0, 0);
                acc = __builtin_amdgcn_mfma_f32_16x16x32_f16(
                                A2[gt][1], B2f1, acc, 0, 0, 0);
                b3u[gt >> 1][(gt & 1) * 2 + 0] = pk_relu_cvt(acc[0], acc[1]);
                b3u[gt >> 1][(gt & 1) * 2 + 1] = pk_relu_cvt(acc[2], acc[3]);
            }

            // L3: o lands in row 0 = lanes q==0, reg 0
            f32x4 acc3 = __builtin_amdgcn_mfma_f32_16x16x32_f16(
                             A3[0], __builtin_bit_cast(f16x8, b3u[0]), zc, 0, 0, 0);
            acc3 = __builtin_amdgcn_mfma_f32_16x16x32_f16(
                             A3[1], __builtin_bit_cast(f16x8, b3u[1]), acc3, 0, 0, 0);

            if (q == 0)
                nvp[s & 1][wave][mt * 16 + mA] = acc3[0];
        }

        // lgkm-only barrier: drain DS writes, sync waves, leave vmcnt in flight
        __builtin_amdgcn_sched_barrier(0);
        asm volatile("s_waitcnt lgkmcnt(0)\n\ts_barrier" ::: "memory");
        __builtin_amdgcn_sched_barrier(0);

        // ---- once-per-lane SDE update of own elements e == lane, lane+64 ----
        {
            const float o0 = nvp[s & 1][0][lane] + b3n0;
            const float o1 = nvp[s & 1][1][lane] + b3n1;
            const float o2 = nvp[s & 1][2][lane] + b3n2;
            const float o3 = nvp[s & 1][3][lane] + b3n3;
            const float e0 = __expf(2.0f * o0);
            const float e1 = __expf(2.0f * o1);
            const float e2 = __expf(2.0f * o2);
            const float e3 = __expf(2.0f * o3);
            const float N0 = 1.0f - 2.0f / (e0 + 1.0f);
            const float N1 = 1.0f - 2.0f / (e1 + 1.0f);
            const float N2 = 1.0f - 2.0f / (e2 + 1.0f);
            const float N3 = 1.0f - 2.0f / (e3 + 1.0f);
            const float z2 = fmaf(rho, z1cA, rho_c * z2cA);
            const float fS = fmaf(N1 * sdtA, z1cA, N0 * dtA);
            const float fV = fmaf(N3 * sdtA, z2, N2 * dtA);
            SregA = fmaf(SregA, fS, SregA);
            VregA = fmaf(VregA, fV, VregA);
            u32x2 pkn;
            pkn[0] = pk2u(SregA, VregA);
            pkn[1] = pk2u(dtA * (float)(s + 1), 1.0f);
            pkx[wave][lane] = pkn;
            z1cA = z1nA; z2cA = z2nA;
        }
        {
            const float o0 = nvp[s & 1][0][64 + lane] + b3n0;
            const float o1 = nvp[s & 1][1][64 + lane] + b3n1;
            const float o2 = nvp[s & 1][2][64 + lane] + b3n2;
            const float o3 = nvp[s & 1][3][64 + lane] + b3n3;
            const float e0 = __expf(2.0f * o0);
            const float e1 = __expf(2.0f * o1);
            const float e2 = __expf(2.0f * o2);
            const float e3 = __expf(2.0f * o3);
            const float N0 = 1.0f - 2.0f / (e0 + 1.0f);
            const float N1 = 1.0f - 2.0f / (e1 + 1.0f);
            const float N2 = 1.0f - 2.0f / (e2 + 1.0f);
            const float N3 = 1.0f - 2.0f / (e3 + 1.0f);
            const float z2 = fmaf(rho, z1cB, rho_c * z2cB);
            const float fS = fmaf(N1 * sdtB, z1cB, N0 * dtB);
            const float fV = fmaf(N3 * sdtB, z2, N2 * dtB);
            SregB = fmaf(SregB, fS, SregB);
            VregB = fmaf(VregB, fV, VregB);
            u32x2 pkn;
            pkn[0] = pk2u(SregB, VregB);
            pkn[1] = pk2u(dtB * (float)(s + 1), 1.0f);
            pkx[wave][64 + lane] = pkn;
            z1cB = z1nB; z2cB = z2nB;
        }
    }

    // ---- payoff: wave 0, lane == element ----
    if (wave == 0) {
        const float TdA = dtA * (float)M_STEPS;
        const float pA  = fmaxf(SregA - Kp[dA_], 0.0f);
        atomicAdd(&out[dA_], __expf(-rf * TdA) * pA * (1.0f / (float)N_SIM));
        const float TdB = dtB * (float)M_STEPS;
        const float pB  = fmaxf(SregB - Kp[dB_], 0.0f);
        atomicAdd(&out[dB_], __expf(-rf * TdB) * pB * (1.0f / (float)N_SIM));
    }
}

extern "C" void kernel_launch(void* const* d_in, const int* in_sizes, int n_in,
                              void* d_out, int out_size, void* d_ws, size_t ws_size,
                              hipStream_t stream)
{
    const float* S0  = (const float*)d_in[0];
    const float* K   = (const float*)d_in[1];
    const float* T   = (const float*)d_in[2];
    const float* rf  = (const float*)d_in[3];
    const float* V0  = (const float*)d_in[4];
    const float* rho = (const float*)d_in[5];
    const float* Z1  = (const float*)d_in[6];
    const float* Z2r = (const float*)d_in[7];
    const float* W1  = (const float*)d_in[8];
    const float* B1  = (const float*)d_in[9];
    const float* W2  = (const float*)d_in[10];
    const float* B2  = (const float*)d_in[11];
    const float* W3  = (const float*)d_in[12];
    const float* B3  = (const float*)d_in[13];
    float* out = (float*)d_out;

    hipMemsetAsync(out, 0, (size_t)out_size * sizeof(float), stream);

    const int total = N_SIM * D_OPT;              // 262144 elements
    const int grid  = total / 128;                // 128 elements per block
    nsde_kernel<<<grid, 256, 0, stream>>>(S0, K, T, rf, V0, rho, Z1, Z2r,
                                          W1, B1, W2, B2, W3, B3, out);
}